// Round 4
// baseline (523.420 us; speedup 1.0000x reference)
//
#include <hip/hip_runtime.h>
#include <hip/hip_bf16.h>

#define NN   50000
#define NE   600000
#define INF  602
#define HID  128
#define OUTF 41
#define NBLK 196   // ceil(NN/256)

// feature-sliced gather geometry: 4 slices x 32 feats; slice s -> XCDs {2s,2s+1}
#define GXCD   128               // gather blocks per XCD
#define GBLKS  (8 * GXCD)        // 1024
#define GCHUNKS (2 * GXCD)       // 256 node-chunks per slice
#define GCHN   ((NN + GCHUNKS - 1) / GCHUNKS)   // 196 nodes per chunk

typedef __attribute__((ext_vector_type(8))) short bf16x8;
typedef __attribute__((ext_vector_type(4))) float f32x4;
typedef __attribute__((ext_vector_type(2))) int i32x2;

__device__ inline unsigned short f2bf(float x) {
    unsigned u = __float_as_uint(x);
    unsigned r = u + 0x7FFF + ((u >> 16) & 1);   // RNE
    return (unsigned short)(r >> 16);
}

#define GLL16(gp, lp) \
    __builtin_amdgcn_global_load_lds((const __attribute__((address_space(1))) unsigned int*)(gp), \
                                     (__attribute__((address_space(3))) unsigned int*)(lp), 16, 0, 0)

// ---------------- degree histogram ----------------
__global__ __launch_bounds__(256) void deg_hist_k(const int* __restrict__ src,
                                                  const int* __restrict__ dst,
                                                  int* __restrict__ cnt_out,
                                                  int* __restrict__ cnt_in, int E) {
    int e = blockIdx.x * 256 + threadIdx.x;
    if (e < E) {
        atomicAdd(&cnt_out[src[e]], 1);
        atomicAdd(&cnt_in[dst[e]], 1);
    }
}

// ---------------- scan pass 1 ----------------
__global__ __launch_bounds__(256) void scan1_k(const int* __restrict__ cnt,
                                               int* __restrict__ rowptr,
                                               int* __restrict__ blockSum) {
    __shared__ int tmp[256];
    int tid = threadIdx.x;
    int i = blockIdx.x * 256 + tid;
    int v = (i < NN) ? cnt[i] : 0;
    tmp[tid] = v;
    __syncthreads();
#pragma unroll
    for (int off = 1; off < 256; off <<= 1) {
        int t = (tid >= off) ? tmp[tid - off] : 0;
        __syncthreads();
        tmp[tid] += t;
        __syncthreads();
    }
    if (i < NN) rowptr[i] = tmp[tid] - v;      // tile-exclusive
    if (tid == 255) blockSum[blockIdx.x] = tmp[255];
}

// ---------------- scan pass 2+3 fused ----------------
__global__ __launch_bounds__(256) void scan23_k(int* __restrict__ rowptr,
                                                const int* __restrict__ blockSum,
                                                int* __restrict__ wcur,
                                                const int* __restrict__ cnt_out,
                                                const int* __restrict__ cnt_in,
                                                float* __restrict__ rs_out,
                                                float* __restrict__ rs_in) {
    const int tid = threadIdx.x;
    const int bid = blockIdx.x;
    int vAll = (tid < NBLK) ? blockSum[tid] : 0;
    int vPre = (tid < bid) ? vAll : 0;
#pragma unroll
    for (int o = 32; o; o >>= 1) {
        vAll += __shfl_down(vAll, o);
        vPre += __shfl_down(vPre, o);
    }
    __shared__ int sA[4], sP[4];
    if ((tid & 63) == 0) { sA[tid >> 6] = vAll; sP[tid >> 6] = vPre; }
    __syncthreads();
    int offAll = sA[0] + sA[1] + sA[2] + sA[3];
    int offPre = sP[0] + sP[1] + sP[2] + sP[3];
    int i = bid * 256 + tid;
    if (i < NN) {
        int r = rowptr[i] + offPre;
        rowptr[i] = r;
        wcur[i] = r;
        int co = cnt_out[i]; if (co < 1) co = 1;
        int ci = cnt_in[i];  if (ci < 1) ci = 1;
        rs_out[i] = rsqrtf((float)co);
        rs_in[i]  = rsqrtf((float)ci);
    }
    if (bid == NBLK - 1 && tid == 0) rowptr[NN] = offAll;
}

// ---------------- CSR fill ----------------
__global__ __launch_bounds__(256) void fill_csr_k(const int* __restrict__ src,
                                                  const int* __restrict__ dst,
                                                  int* __restrict__ wcur,
                                                  int* __restrict__ csrsrc, int E) {
    int e = blockIdx.x * 256 + threadIdx.x;
    if (e < E) {
        int p = atomicAdd(&wcur[dst[e]], 1);
        csrsrc[p] = src[e];
    }
}

// ---------------- weight prep (all weights, one dispatch) + cnt zeroing ----------------
__device__ inline void prep_w_body(const float* __restrict__ W, int K,
                                   unsigned short* __restrict__ out, int total4, int i) {
    if (i >= total4) return;
    int col = i & 127;
    int k4 = (i >> 7) << 2;
    short4 h;
    h.x = (short)f2bf((k4 + 0 < K) ? W[(size_t)(k4 + 0) * HID + col] : 0.f);
    h.y = (short)f2bf((k4 + 1 < K) ? W[(size_t)(k4 + 1) * HID + col] : 0.f);
    h.z = (short)f2bf((k4 + 2 < K) ? W[(size_t)(k4 + 2) * HID + col] : 0.f);
    h.w = (short)f2bf((k4 + 3 < K) ? W[(size_t)(k4 + 3) * HID + col] : 0.f);
    *(short4*)&out[(size_t)(k4 >> 3) * 1024 + col * 8 + (k4 & 7)] = h;
}

__global__ __launch_bounds__(256) void prep_all_k(const float* __restrict__ W1,
                                                  const float* __restrict__ W2,
                                                  const float* __restrict__ W3,
                                                  unsigned short* __restrict__ W1t,
                                                  unsigned short* __restrict__ W2t,
                                                  unsigned short* __restrict__ W3t,
                                                  int* __restrict__ cnt) {
    int b = blockIdx.x;
    if (b < 80) {
        int t = b * 256 + threadIdx.x;             // 0..20479
        prep_w_body(W1, INF, W1t, 20480, t);
        for (int i = t; i < 2 * NN; i += 20480) cnt[i] = 0;
    } else if (b < 96) {
        prep_w_body(W2, HID, W2t, 4096, (b - 80) * 256 + threadIdx.x);
    } else {
        prep_w_body(W3, HID, W3t, 4096, (b - 96) * 256 + threadIdx.x);
    }
}

// ============ gemm1 (chunked BK=128): H[n,128] = bf16( rs_out[row] * (A[row,:] @ W1) ) ============
__global__ __launch_bounds__(256) void gemm1_k(const float* __restrict__ A,
                                               const unsigned short* __restrict__ Wt,
                                               const float* __restrict__ rs_out,
                                               unsigned short* __restrict__ H, int n) {
    __shared__ __attribute__((aligned(16))) short As[64 * 136];   // 64 rows x 128 k, stride 136
    __shared__ __attribute__((aligned(16))) short Bs[16 * 1024];  // 16 kgroups x [col][8k]

    const int tid = threadIdx.x;
    const int wave = tid >> 6;
    const int lane = tid & 63;
    const int quad = lane >> 4;
    const int l16 = lane & 15;
    const int rowBase = blockIdx.x * 64;
    const int tileBase = rowBase + wave * 16;

    float4 apf[8];
    auto loadA = [&](int ch) {   // coalesced: 32 consecutive lanes span one row's 128 floats
        int kb = ch * 128;
#pragma unroll
        for (int c = 0; c < 8; ++c) {
            int f = c * 256 + tid;
            int row = f >> 5;
            int kc = (f & 31) << 2;
            int grow = rowBase + row;
            int gk = kb + kc;
            float4 v = {0.f, 0.f, 0.f, 0.f};
            if (grow < n) {
                if (gk + 3 < INF) {
                    v = *(const float4*)(A + (size_t)grow * INF + gk);
                } else {
                    if (gk + 0 < INF) v.x = A[(size_t)grow * INF + gk + 0];
                    if (gk + 1 < INF) v.y = A[(size_t)grow * INF + gk + 1];
                    if (gk + 2 < INF) v.z = A[(size_t)grow * INF + gk + 2];
                }
            }
            apf[c] = v;
        }
    };
    auto storeA = [&]() {
#pragma unroll
        for (int c = 0; c < 8; ++c) {
            int f = c * 256 + tid;
            int row = f >> 5;
            int kc = (f & 31) << 2;
            short4 h;
            h.x = (short)f2bf(apf[c].x); h.y = (short)f2bf(apf[c].y);
            h.z = (short)f2bf(apf[c].z); h.w = (short)f2bf(apf[c].w);
            *(short4*)&As[row * 136 + kc] = h;
        }
    };
    auto issueB = [&](int ch) {  // 32KB = 32 x 1KB wave-DMA
#pragma unroll
        for (int c = 0; c < 8; ++c)
            GLL16(Wt + (size_t)ch * 16384 + c * 2048 + tid * 8, &Bs[c * 2048 + tid * 8]);
    };

    f32x4 acc[8];
#pragma unroll
    for (int j = 0; j < 8; ++j) acc[j] = (f32x4){0.f, 0.f, 0.f, 0.f};

    loadA(0);
    for (int ch = 0; ch < 5; ++ch) {
        __syncthreads();             // WAR: everyone done reading previous chunk's As/Bs
        issueB(ch);
        storeA();
        __syncthreads();             // arrival: DMA drained + As visible
        if (ch + 1 < 5) loadA(ch + 1);   // prefetch next A under this chunk's compute
#pragma unroll
        for (int s = 0; s < 4; ++s) {
            bf16x8 af = *(const bf16x8*)&As[(wave * 16 + l16) * 136 + s * 32 + quad * 8];
            const short* bg = &Bs[(s * 4 + quad) * 1024 + l16 * 8];
#pragma unroll
            for (int nt = 0; nt < 8; ++nt) {
                bf16x8 bf = *(const bf16x8*)(bg + nt * 128);
                acc[nt] = __builtin_amdgcn_mfma_f32_16x16x32_bf16(af, bf, acc[nt], 0, 0, 0);
            }
        }
    }

    // epilogue: C/D layout col = nt*16 + l16, row = tileBase + quad*4 + r
#pragma unroll
    for (int r = 0; r < 4; ++r) {
        int row = tileBase + quad * 4 + r;
        if (row < n) {
            float ro = rs_out[row];
#pragma unroll
            for (int nt = 0; nt < 8; ++nt)
                H[(size_t)row * HID + nt * 16 + l16] = f2bf(acc[nt][r] * ro);
        }
    }
}

// ============ gemm_hid: H[n,128] = bf16( Abf16[n,128] @ W[128,128] ), whole-W DMA to LDS ============
__global__ __launch_bounds__(256) void gemm_hid_k(const unsigned short* __restrict__ A,
                                                  const unsigned short* __restrict__ Wt,
                                                  unsigned short* __restrict__ H, int n) {
    __shared__ __attribute__((aligned(16))) short As[64 * 136];
    __shared__ __attribute__((aligned(16))) short Bs[16384];

    const int tid = threadIdx.x;
    const int wave = tid >> 6;
    const int lane = tid & 63;
    const int quad = lane >> 4;
    const int l16 = lane & 15;
    const int wm = wave >> 1;
    const int wn = wave & 1;
    const int rowBase = blockIdx.x * 64;

#pragma unroll
    for (int c = 0; c < 8; ++c)
        GLL16(Wt + c * 2048 + tid * 8, &Bs[c * 2048 + tid * 8]);

#pragma unroll
    for (int c = 0; c < 4; ++c) {
        int f = c * 256 + tid;
        int row = f >> 4;
        int k16 = (f & 15) << 3;
        int grow = rowBase + row;
        int4 v = {0, 0, 0, 0};
        if (grow < n) v = *(const int4*)(A + (size_t)grow * HID + k16);
        *(int4*)&As[row * 136 + k16] = v;
    }
    __syncthreads();

    f32x4 acc[2][4];
#pragma unroll
    for (int i = 0; i < 2; ++i)
#pragma unroll
        for (int j = 0; j < 4; ++j) acc[i][j] = (f32x4){0.f, 0.f, 0.f, 0.f};

#pragma unroll
    for (int kq = 0; kq < 4; ++kq) {
        bf16x8 af[2], bfr[4];
#pragma unroll
        for (int mt = 0; mt < 2; ++mt)
            af[mt] = *(const bf16x8*)&As[(wm * 32 + mt * 16 + l16) * 136 + kq * 32 + quad * 8];
#pragma unroll
        for (int nt = 0; nt < 4; ++nt)
            bfr[nt] = *(const bf16x8*)&Bs[(kq * 4 + quad) * 1024 + (wn * 64 + nt * 16 + l16) * 8];
#pragma unroll
        for (int mt = 0; mt < 2; ++mt)
#pragma unroll
            for (int nt = 0; nt < 4; ++nt)
                acc[mt][nt] = __builtin_amdgcn_mfma_f32_16x16x32_bf16(af[mt], bfr[nt], acc[mt][nt], 0, 0, 0);
    }

#pragma unroll
    for (int mt = 0; mt < 2; ++mt)
#pragma unroll
        for (int r = 0; r < 4; ++r) {
            int row = rowBase + wm * 32 + mt * 16 + quad * 4 + r;
            if (row < n) {
#pragma unroll
                for (int nt = 0; nt < 4; ++nt) {
                    int col = wn * 64 + nt * 16 + l16;
                    H[(size_t)row * HID + col] = f2bf(acc[mt][nt][r]);
                }
            }
        }
}

// ---------------- feature-sliced, XCD-pinned gather ----------------
// 4 slices x 32 features. Block b: xcd = b%8 (HW round-robin), slice = xcd>>1,
// chunk = (b>>3)*2 + (xcd&1). Each XCD only ever touches ITS 3.2 MB slice of Hin
// -> gather row reads become per-XCD L2 hits instead of LLC-random (72 MB L2 miss
// observed in R3's ffc_k). Outputs use non-temporal stores to not evict the slice.
// Per-node accumulation order identical to before (CSR j-order) -> same math.
__global__ __launch_bounds__(256) void gath_slice_k(const unsigned short* __restrict__ Hin,
                                                    const int* __restrict__ rowptr,
                                                    const int* __restrict__ csrsrc,
                                                    const float* __restrict__ rs_in,
                                                    const float* __restrict__ rs_out,
                                                    const float* __restrict__ bias,
                                                    const float* __restrict__ residIn,   // nullable
                                                    float* __restrict__ residOut,        // nullable
                                                    unsigned short* __restrict__ outXs,  // nullable (bf16, *ro)
                                                    float* __restrict__ outX,            // nullable (fp32)
                                                    int n) {
    const int b = blockIdx.x;
    const int xcd = b & 7;
    const int slice = xcd >> 1;                    // 0..3
    const int chunk = ((b >> 3) << 1) + (xcd & 1); // 0..GCHUNKS-1
    const int n0 = chunk * GCHN;
    const int n1 = min(n0 + GCHN, n);

    const int tid = threadIdx.x;
    const int wave = tid >> 6;
    const int lane = tid & 63;
    const int g = lane >> 3;        // node group 0..7
    const int l8 = lane & 7;        // lane in group
    const int gbase = g << 3;
    const int col = slice * 32 + l8 * 4;   // this lane's 4 features

    const float4 bb = *(const float4*)(bias + col);

    for (int nb = n0 + wave * 8; nb < n1; nb += 32) {
        int node = nb + g;
        bool alive = node < n1;
        int beg = 0, end = 0;
        if (alive) { beg = rowptr[node]; end = rowptr[node + 1]; }

        float a0 = 0.f, a1 = 0.f, a2 = 0.f, a3 = 0.f;

        for (int base = beg; base < end; base += 8) {
            int m = end - base; if (m > 8) m = 8;
            int idx = (l8 < m) ? csrsrc[base + l8] : 0;
            int j = 0;
            for (; j + 3 < m; j += 4) {
                int s0 = __shfl(idx, gbase | j);
                int s1 = __shfl(idx, gbase | (j + 1));
                int s2 = __shfl(idx, gbase | (j + 2));
                int s3 = __shfl(idx, gbase | (j + 3));
                int2 u0 = *(const int2*)(Hin + (size_t)s0 * HID + col);
                int2 u1 = *(const int2*)(Hin + (size_t)s1 * HID + col);
                int2 u2 = *(const int2*)(Hin + (size_t)s2 * HID + col);
                int2 u3 = *(const int2*)(Hin + (size_t)s3 * HID + col);
#pragma unroll
                for (int q = 0; q < 4; ++q) {
                    int2 u = (q == 0) ? u0 : (q == 1) ? u1 : (q == 2) ? u2 : u3;
                    unsigned x = (unsigned)u.x, y = (unsigned)u.y;
                    a0 += __uint_as_float(x << 16); a1 += __uint_as_float(x & 0xFFFF0000u);
                    a2 += __uint_as_float(y << 16); a3 += __uint_as_float(y & 0xFFFF0000u);
                }
            }
            for (; j < m; ++j) {
                int s = __shfl(idx, gbase | j);
                int2 u = *(const int2*)(Hin + (size_t)s * HID + col);
                unsigned x = (unsigned)u.x, y = (unsigned)u.y;
                a0 += __uint_as_float(x << 16); a1 += __uint_as_float(x & 0xFFFF0000u);
                a2 += __uint_as_float(y << 16); a3 += __uint_as_float(y & 0xFFFF0000u);
            }
        }

        if (alive) {
            float ri = rs_in[node];
            float v0 = fmaxf(a0 * ri + bb.x, 0.f);
            float v1 = fmaxf(a1 * ri + bb.y, 0.f);
            float v2 = fmaxf(a2 * ri + bb.z, 0.f);
            float v3 = fmaxf(a3 * ri + bb.w, 0.f);
            size_t o = (size_t)node * HID + col;
            if (residOut)
                __builtin_nontemporal_store((f32x4){v0, v1, v2, v3}, (f32x4*)(residOut + o));
            if (residIn) {
                f32x4 r = __builtin_nontemporal_load((const f32x4*)(residIn + o));
                v0 = fmaxf(v0 + r[0], 0.f);
                v1 = fmaxf(v1 + r[1], 0.f);
                v2 = fmaxf(v2 + r[2], 0.f);
                v3 = fmaxf(v3 + r[3], 0.f);
            }
            if (outXs) {
                float ro = rs_out[node];
                i32x2 h;
                h[0] = (int)(((unsigned)f2bf(v1 * ro) << 16) | f2bf(v0 * ro));
                h[1] = (int)(((unsigned)f2bf(v3 * ro) << 16) | f2bf(v2 * ro));
                __builtin_nontemporal_store(h, (i32x2*)(outXs + o));
            }
            if (outX)
                __builtin_nontemporal_store((f32x4){v0, v1, v2, v3}, (f32x4*)(outX + o));
        }
    }
}

// ---------------- final FC: out[n,41] = X[n,128] @ Wfc + bfc ----------------
__global__ __launch_bounds__(256) void fc_k(const float* __restrict__ X,
                                            const float* __restrict__ Wfc,
                                            const float* __restrict__ bfc,
                                            float* __restrict__ out, int n) {
    __shared__ float Ws[HID * OUTF];
    __shared__ float Xs[4][HID];
    int tid = threadIdx.x;
    for (int i = tid; i < HID * OUTF; i += 256) Ws[i] = Wfc[i];
    int rowBase = blockIdx.x * 4;
    for (int i = tid; i < 4 * HID; i += 256) {
        int r = i >> 7, c = i & 127;
        int gr = rowBase + r;
        Xs[r][c] = (gr < n) ? X[(size_t)gr * HID + c] : 0.f;
    }
    __syncthreads();
    int wv = tid >> 6, lane = tid & 63;
    int row = rowBase + wv;
    if (row < n && lane < OUTF) {
        float acc = bfc[lane];
#pragma unroll 8
        for (int k = 0; k < HID; ++k) acc += Xs[wv][k] * Ws[k * OUTF + lane];
        out[(size_t)row * OUTF + lane] = acc;
    }
}

extern "C" void kernel_launch(void* const* d_in, const int* in_sizes, int n_in,
                              void* d_out, int out_size, void* d_ws, size_t ws_size,
                              hipStream_t stream) {
    const float* feat = (const float*)d_in[0];
    const int* src = (const int*)d_in[1];
    const int* dst = (const int*)d_in[2];
    const float* W1 = (const float*)d_in[3];
    const float* b1 = (const float*)d_in[4];
    const float* W2 = (const float*)d_in[5];
    const float* b2 = (const float*)d_in[6];
    const float* W3 = (const float*)d_in[7];
    const float* b3 = (const float*)d_in[8];
    const float* Wfc = (const float*)d_in[9];
    const float* bfc = (const float*)d_in[10];
    float* out = (float*)d_out;

    char* w = (char*)d_ws;
    auto alloc = [&](size_t b) -> void* {
        void* p = (void*)w;
        w += (b + 255) & ~(size_t)255;
        return p;
    };
    int* cnt = (int*)alloc(2 * NN * sizeof(int));   // [cnt_out | cnt_in], zeroed in prep_all
    int* cnt_out = cnt;
    int* cnt_in  = cnt + NN;
    int* rowptr  = (int*)alloc((NN + 1) * sizeof(int));
    int* wcur    = (int*)alloc(NN * sizeof(int));
    int* csrsrc  = (int*)alloc(NE * sizeof(int));
    int* blockSum = (int*)alloc(NBLK * sizeof(int));
    float* rs_out = (float*)alloc(NN * sizeof(float));
    float* rs_in  = (float*)alloc(NN * sizeof(float));
    unsigned short* W1t = (unsigned short*)alloc(10 * 8192 * sizeof(unsigned short));
    unsigned short* W2t = (unsigned short*)alloc(16384 * sizeof(unsigned short));
    unsigned short* W3t = (unsigned short*)alloc(16384 * sizeof(unsigned short));
    unsigned short* Ha = (unsigned short*)alloc((size_t)NN * HID * sizeof(unsigned short));
    unsigned short* Hb = (unsigned short*)alloc((size_t)NN * HID * sizeof(unsigned short));
    unsigned short* Xb = (unsigned short*)alloc((size_t)NN * HID * sizeof(unsigned short));
    float* resid = (float*)alloc((size_t)NN * HID * sizeof(float));
    float* Xfc   = (float*)alloc((size_t)NN * HID * sizeof(float));

    prep_all_k<<<112, 256, 0, stream>>>(W1, W2, W3, W1t, W2t, W3t, cnt);
    deg_hist_k<<<(NE + 255) / 256, 256, 0, stream>>>(src, dst, cnt_out, cnt_in, NE);
    scan1_k<<<NBLK, 256, 0, stream>>>(cnt_in, rowptr, blockSum);
    scan23_k<<<NBLK, 256, 0, stream>>>(rowptr, blockSum, wcur, cnt_out, cnt_in, rs_out, rs_in);
    fill_csr_k<<<(NE + 255) / 256, 256, 0, stream>>>(src, dst, wcur, csrsrc, NE);

    const int gblk = (NN + 63) / 64;    // 782
    // L1 GEMM: Ha = bf16(rs_out ∘ (feat @ W1))
    gemm1_k<<<gblk, 256, 0, stream>>>(feat, W1t, rs_out, Ha, NN);
    // g1: Xb = bf16(relu(agg(Ha)*ri+b1) * ro)
    gath_slice_k<<<GBLKS, 256, 0, stream>>>(Ha, rowptr, csrsrc, rs_in, rs_out, b1,
                                            nullptr, nullptr, Xb, nullptr, NN);
    // L2 GEMM: Hb = bf16(Xb @ W2)
    gemm_hid_k<<<gblk, 256, 0, stream>>>(Xb, W2t, Hb, NN);
    // g2: resid = x2 fp32 (post-relu), Xb = bf16(x2 * ro)
    gath_slice_k<<<GBLKS, 256, 0, stream>>>(Hb, rowptr, csrsrc, rs_in, rs_out, b2,
                                            nullptr, resid, Xb, nullptr, NN);
    // L3 GEMM: Ha = bf16(Xb @ W3)
    gemm_hid_k<<<gblk, 256, 0, stream>>>(Xb, W3t, Ha, NN);
    // g3: Xfc = relu(relu(agg(Ha)*ri+b3) + resid)
    gath_slice_k<<<GBLKS, 256, 0, stream>>>(Ha, rowptr, csrsrc, rs_in, rs_out, b3,
                                            resid, nullptr, nullptr, Xfc, NN);
    // FC
    fc_k<<<(NN + 3) / 4, 256, 0, stream>>>(Xfc, Wfc, bfc, out, NN);
}

// Round 5
// 499.037 us; speedup vs baseline: 1.0489x; 1.0489x over previous
//
#include <hip/hip_runtime.h>
#include <hip/hip_bf16.h>

#define NN   50000
#define NE   600000
#define INF  602
#define HID  128
#define OUTF 41
#define NBLK 196   // ceil(NN/256)

// slab-sliced gather geometry: H stored as 4 slabs [slab][NN][32feats] (3.2 MB each,
// fits 4 MiB per-XCD L2). slab s is only ever read by XCDs {2s, 2s+1} (blockIdx%8).
#define NSLAB  4
#define SLABF  32
#define GXCD   256               // gather blocks per XCD
#define GBLKS  (8 * GXCD)        // 2048
#define GCHUNKS (2 * GXCD)       // 512 node-chunks per slice
#define GCHN   ((NN + GCHUNKS - 1) / GCHUNKS)   // 98 nodes per chunk

typedef __attribute__((ext_vector_type(8))) short bf16x8;
typedef __attribute__((ext_vector_type(4))) float f32x4;
typedef __attribute__((ext_vector_type(2))) int i32x2;

__device__ inline unsigned short f2bf(float x) {
    unsigned u = __float_as_uint(x);
    unsigned r = u + 0x7FFF + ((u >> 16) & 1);   // RNE
    return (unsigned short)(r >> 16);
}

#define GLL16(gp, lp) \
    __builtin_amdgcn_global_load_lds((const __attribute__((address_space(1))) unsigned int*)(gp), \
                                     (__attribute__((address_space(3))) unsigned int*)(lp), 16, 0, 0)

// ---------------- degree histogram ----------------
__global__ __launch_bounds__(256) void deg_hist_k(const int* __restrict__ src,
                                                  const int* __restrict__ dst,
                                                  int* __restrict__ cnt_out,
                                                  int* __restrict__ cnt_in, int E) {
    int e = blockIdx.x * 256 + threadIdx.x;
    if (e < E) {
        atomicAdd(&cnt_out[src[e]], 1);
        atomicAdd(&cnt_in[dst[e]], 1);
    }
}

// ---------------- scan pass 1 ----------------
__global__ __launch_bounds__(256) void scan1_k(const int* __restrict__ cnt,
                                               int* __restrict__ rowptr,
                                               int* __restrict__ blockSum) {
    __shared__ int tmp[256];
    int tid = threadIdx.x;
    int i = blockIdx.x * 256 + tid;
    int v = (i < NN) ? cnt[i] : 0;
    tmp[tid] = v;
    __syncthreads();
#pragma unroll
    for (int off = 1; off < 256; off <<= 1) {
        int t = (tid >= off) ? tmp[tid - off] : 0;
        __syncthreads();
        tmp[tid] += t;
        __syncthreads();
    }
    if (i < NN) rowptr[i] = tmp[tid] - v;      // tile-exclusive
    if (tid == 255) blockSum[blockIdx.x] = tmp[255];
}

// ---------------- scan pass 2+3 fused ----------------
__global__ __launch_bounds__(256) void scan23_k(int* __restrict__ rowptr,
                                                const int* __restrict__ blockSum,
                                                int* __restrict__ wcur,
                                                const int* __restrict__ cnt_out,
                                                const int* __restrict__ cnt_in,
                                                float* __restrict__ rs_out,
                                                float* __restrict__ rs_in) {
    const int tid = threadIdx.x;
    const int bid = blockIdx.x;
    int vAll = (tid < NBLK) ? blockSum[tid] : 0;
    int vPre = (tid < bid) ? vAll : 0;
#pragma unroll
    for (int o = 32; o; o >>= 1) {
        vAll += __shfl_down(vAll, o);
        vPre += __shfl_down(vPre, o);
    }
    __shared__ int sA[4], sP[4];
    if ((tid & 63) == 0) { sA[tid >> 6] = vAll; sP[tid >> 6] = vPre; }
    __syncthreads();
    int offAll = sA[0] + sA[1] + sA[2] + sA[3];
    int offPre = sP[0] + sP[1] + sP[2] + sP[3];
    int i = bid * 256 + tid;
    if (i < NN) {
        int r = rowptr[i] + offPre;
        rowptr[i] = r;
        wcur[i] = r;
        int co = cnt_out[i]; if (co < 1) co = 1;
        int ci = cnt_in[i];  if (ci < 1) ci = 1;
        rs_out[i] = rsqrtf((float)co);
        rs_in[i]  = rsqrtf((float)ci);
    }
    if (bid == NBLK - 1 && tid == 0) rowptr[NN] = offAll;
}

// ---------------- CSR fill ----------------
__global__ __launch_bounds__(256) void fill_csr_k(const int* __restrict__ src,
                                                  const int* __restrict__ dst,
                                                  int* __restrict__ wcur,
                                                  int* __restrict__ csrsrc, int E) {
    int e = blockIdx.x * 256 + threadIdx.x;
    if (e < E) {
        int p = atomicAdd(&wcur[dst[e]], 1);
        csrsrc[p] = src[e];
    }
}

// ---------------- weight prep (all weights, one dispatch) + cnt zeroing ----------------
__device__ inline void prep_w_body(const float* __restrict__ W, int K,
                                   unsigned short* __restrict__ out, int total4, int i) {
    if (i >= total4) return;
    int col = i & 127;
    int k4 = (i >> 7) << 2;
    short4 h;
    h.x = (short)f2bf((k4 + 0 < K) ? W[(size_t)(k4 + 0) * HID + col] : 0.f);
    h.y = (short)f2bf((k4 + 1 < K) ? W[(size_t)(k4 + 1) * HID + col] : 0.f);
    h.z = (short)f2bf((k4 + 2 < K) ? W[(size_t)(k4 + 2) * HID + col] : 0.f);
    h.w = (short)f2bf((k4 + 3 < K) ? W[(size_t)(k4 + 3) * HID + col] : 0.f);
    *(short4*)&out[(size_t)(k4 >> 3) * 1024 + col * 8 + (k4 & 7)] = h;
}

__global__ __launch_bounds__(256) void prep_all_k(const float* __restrict__ W1,
                                                  const float* __restrict__ W2,
                                                  const float* __restrict__ W3,
                                                  unsigned short* __restrict__ W1t,
                                                  unsigned short* __restrict__ W2t,
                                                  unsigned short* __restrict__ W3t,
                                                  int* __restrict__ cnt) {
    int b = blockIdx.x;
    if (b < 80) {
        int t = b * 256 + threadIdx.x;             // 0..20479
        prep_w_body(W1, INF, W1t, 20480, t);
        for (int i = t; i < 2 * NN; i += 20480) cnt[i] = 0;
    } else if (b < 96) {
        prep_w_body(W2, HID, W2t, 4096, (b - 80) * 256 + threadIdx.x);
    } else {
        prep_w_body(W3, HID, W3t, 4096, (b - 96) * 256 + threadIdx.x);
    }
}

// ============ gemm1 (chunked BK=128): Hs(slab) = bf16( rs_out[row] * (A[row,:] @ W1) ) ============
__global__ __launch_bounds__(256) void gemm1_k(const float* __restrict__ A,
                                               const unsigned short* __restrict__ Wt,
                                               const float* __restrict__ rs_out,
                                               unsigned short* __restrict__ H, int n) {
    __shared__ __attribute__((aligned(16))) short As[64 * 136];   // 64 rows x 128 k, stride 136
    __shared__ __attribute__((aligned(16))) short Bs[16 * 1024];  // 16 kgroups x [col][8k]

    const int tid = threadIdx.x;
    const int wave = tid >> 6;
    const int lane = tid & 63;
    const int quad = lane >> 4;
    const int l16 = lane & 15;
    const int rowBase = blockIdx.x * 64;
    const int tileBase = rowBase + wave * 16;

    float4 apf[8];
    auto loadA = [&](int ch) {   // coalesced: 32 consecutive lanes span one row's 128 floats
        int kb = ch * 128;
#pragma unroll
        for (int c = 0; c < 8; ++c) {
            int f = c * 256 + tid;
            int row = f >> 5;
            int kc = (f & 31) << 2;
            int grow = rowBase + row;
            int gk = kb + kc;
            float4 v = {0.f, 0.f, 0.f, 0.f};
            if (grow < n) {
                if (gk + 3 < INF) {
                    v = *(const float4*)(A + (size_t)grow * INF + gk);
                } else {
                    if (gk + 0 < INF) v.x = A[(size_t)grow * INF + gk + 0];
                    if (gk + 1 < INF) v.y = A[(size_t)grow * INF + gk + 1];
                    if (gk + 2 < INF) v.z = A[(size_t)grow * INF + gk + 2];
                }
            }
            apf[c] = v;
        }
    };
    auto storeA = [&]() {
#pragma unroll
        for (int c = 0; c < 8; ++c) {
            int f = c * 256 + tid;
            int row = f >> 5;
            int kc = (f & 31) << 2;
            short4 h;
            h.x = (short)f2bf(apf[c].x); h.y = (short)f2bf(apf[c].y);
            h.z = (short)f2bf(apf[c].z); h.w = (short)f2bf(apf[c].w);
            *(short4*)&As[row * 136 + kc] = h;
        }
    };
    auto issueB = [&](int ch) {  // 32KB = 32 x 1KB wave-DMA
#pragma unroll
        for (int c = 0; c < 8; ++c)
            GLL16(Wt + (size_t)ch * 16384 + c * 2048 + tid * 8, &Bs[c * 2048 + tid * 8]);
    };

    f32x4 acc[8];
#pragma unroll
    for (int j = 0; j < 8; ++j) acc[j] = (f32x4){0.f, 0.f, 0.f, 0.f};

    loadA(0);
    for (int ch = 0; ch < 5; ++ch) {
        __syncthreads();             // WAR: everyone done reading previous chunk's As/Bs
        issueB(ch);
        storeA();
        __syncthreads();             // arrival: DMA drained + As visible
        if (ch + 1 < 5) loadA(ch + 1);   // prefetch next A under this chunk's compute
#pragma unroll
        for (int s = 0; s < 4; ++s) {
            bf16x8 af = *(const bf16x8*)&As[(wave * 16 + l16) * 136 + s * 32 + quad * 8];
            const short* bg = &Bs[(s * 4 + quad) * 1024 + l16 * 8];
#pragma unroll
            for (int nt = 0; nt < 8; ++nt) {
                bf16x8 bf = *(const bf16x8*)(bg + nt * 128);
                acc[nt] = __builtin_amdgcn_mfma_f32_16x16x32_bf16(af, bf, acc[nt], 0, 0, 0);
            }
        }
    }

    // epilogue -> slab layout: col = nt*16+l16; slab = nt>>1; off = (nt&1)*16+l16
#pragma unroll
    for (int r = 0; r < 4; ++r) {
        int row = tileBase + quad * 4 + r;
        if (row < n) {
            float ro = rs_out[row];
#pragma unroll
            for (int nt = 0; nt < 8; ++nt)
                H[(size_t)(nt >> 1) * (NN * SLABF) + (size_t)row * SLABF + (nt & 1) * 16 + l16] =
                    f2bf(acc[nt][r] * ro);
        }
    }
}

// ============ gemm_hid: Hs(slab) = bf16( Abf16[n,128] @ W[128,128] ), whole-W DMA to LDS ============
__global__ __launch_bounds__(256) void gemm_hid_k(const unsigned short* __restrict__ A,
                                                  const unsigned short* __restrict__ Wt,
                                                  unsigned short* __restrict__ H, int n) {
    __shared__ __attribute__((aligned(16))) short As[64 * 136];
    __shared__ __attribute__((aligned(16))) short Bs[16384];

    const int tid = threadIdx.x;
    const int wave = tid >> 6;
    const int lane = tid & 63;
    const int quad = lane >> 4;
    const int l16 = lane & 15;
    const int wm = wave >> 1;
    const int wn = wave & 1;
    const int rowBase = blockIdx.x * 64;

#pragma unroll
    for (int c = 0; c < 8; ++c)
        GLL16(Wt + c * 2048 + tid * 8, &Bs[c * 2048 + tid * 8]);

#pragma unroll
    for (int c = 0; c < 4; ++c) {
        int f = c * 256 + tid;
        int row = f >> 4;
        int k16 = (f & 15) << 3;
        int grow = rowBase + row;
        int4 v = {0, 0, 0, 0};
        if (grow < n) v = *(const int4*)(A + (size_t)grow * HID + k16);
        *(int4*)&As[row * 136 + k16] = v;
    }
    __syncthreads();

    f32x4 acc[2][4];
#pragma unroll
    for (int i = 0; i < 2; ++i)
#pragma unroll
        for (int j = 0; j < 4; ++j) acc[i][j] = (f32x4){0.f, 0.f, 0.f, 0.f};

#pragma unroll
    for (int kq = 0; kq < 4; ++kq) {
        bf16x8 af[2], bfr[4];
#pragma unroll
        for (int mt = 0; mt < 2; ++mt)
            af[mt] = *(const bf16x8*)&As[(wm * 32 + mt * 16 + l16) * 136 + kq * 32 + quad * 8];
#pragma unroll
        for (int nt = 0; nt < 4; ++nt)
            bfr[nt] = *(const bf16x8*)&Bs[(kq * 4 + quad) * 1024 + (wn * 64 + nt * 16 + l16) * 8];
#pragma unroll
        for (int mt = 0; mt < 2; ++mt)
#pragma unroll
            for (int nt = 0; nt < 4; ++nt)
                acc[mt][nt] = __builtin_amdgcn_mfma_f32_16x16x32_bf16(af[mt], bfr[nt], acc[mt][nt], 0, 0, 0);
    }

#pragma unroll
    for (int mt = 0; mt < 2; ++mt)
#pragma unroll
        for (int r = 0; r < 4; ++r) {
            int row = rowBase + wm * 32 + mt * 16 + quad * 4 + r;
            if (row < n) {
#pragma unroll
                for (int nt = 0; nt < 4; ++nt) {
                    int cg = wn * 4 + nt;   // col group 0..7 (16 cols each)
                    H[(size_t)(cg >> 1) * (NN * SLABF) + (size_t)row * SLABF + (cg & 1) * 16 + l16] =
                        f2bf(acc[mt][nt][r]);
                }
            }
        }
}

// ---------------- slab-sliced, XCD-pinned gather ----------------
// Block b: xcd = b%8, slice = xcd>>1, chunk = (b>>3)*2 + (xcd&1). Each XCD reads ONLY
// its 3.2 MB slab (contiguous, no line straddle) -> fully L2-resident after warm-up.
// csrsrc / resid streams use non-temporal ops to avoid evicting the slab.
// Per-node accumulation order identical to R2 (sequential CSR order) -> same math.
__global__ __launch_bounds__(256) void gath_slab_k(const unsigned short* __restrict__ Hs,
                                                   const int* __restrict__ rowptr,
                                                   const int* __restrict__ csrsrc,
                                                   const float* __restrict__ rs_in,
                                                   const float* __restrict__ rs_out,
                                                   const float* __restrict__ bias,
                                                   const float* __restrict__ residIn,   // nullable
                                                   float* __restrict__ residOut,        // nullable
                                                   unsigned short* __restrict__ outXs,  // nullable (bf16, *ro)
                                                   float* __restrict__ outX,            // nullable (fp32)
                                                   int n) {
    const int b = blockIdx.x;
    const int xcd = b & 7;
    const int slice = xcd >> 1;                    // 0..3
    const int chunk = ((b >> 3) << 1) + (xcd & 1); // 0..GCHUNKS-1
    const int n0 = chunk * GCHN;
    const int n1 = min(n0 + GCHN, n);
    const unsigned short* __restrict__ slab = Hs + (size_t)slice * (NN * SLABF);

    const int tid = threadIdx.x;
    const int wave = tid >> 6;
    const int lane = tid & 63;
    const int g = lane >> 3;        // node group 0..7
    const int l8 = lane & 7;        // lane in group
    const int gbase = g << 3;
    const int colLoc = l8 * 4;                 // feature offset inside slab
    const int col = slice * SLABF + colLoc;    // global feature index

    const float4 bb = *(const float4*)(bias + col);

    for (int nb = n0 + wave * 8; nb < n1; nb += 32) {
        int node = nb + g;
        bool alive = node < n1;
        int beg = 0, end = 0;
        if (alive) { beg = rowptr[node]; end = rowptr[node + 1]; }

        float a0 = 0.f, a1 = 0.f, a2 = 0.f, a3 = 0.f;

        for (int base = beg; base < end; base += 8) {
            int m = end - base; if (m > 8) m = 8;
            int idx = (l8 < m) ? __builtin_nontemporal_load(csrsrc + base + l8) : 0;
            int j = 0;
            for (; j + 3 < m; j += 4) {
                int s0 = __shfl(idx, gbase | j);
                int s1 = __shfl(idx, gbase | (j + 1));
                int s2 = __shfl(idx, gbase | (j + 2));
                int s3 = __shfl(idx, gbase | (j + 3));
                int2 u0 = *(const int2*)(slab + s0 * SLABF + colLoc);
                int2 u1 = *(const int2*)(slab + s1 * SLABF + colLoc);
                int2 u2 = *(const int2*)(slab + s2 * SLABF + colLoc);
                int2 u3 = *(const int2*)(slab + s3 * SLABF + colLoc);
#pragma unroll
                for (int q = 0; q < 4; ++q) {
                    int2 u = (q == 0) ? u0 : (q == 1) ? u1 : (q == 2) ? u2 : u3;
                    unsigned x = (unsigned)u.x, y = (unsigned)u.y;
                    a0 += __uint_as_float(x << 16); a1 += __uint_as_float(x & 0xFFFF0000u);
                    a2 += __uint_as_float(y << 16); a3 += __uint_as_float(y & 0xFFFF0000u);
                }
            }
            for (; j < m; ++j) {
                int s = __shfl(idx, gbase | j);
                int2 u = *(const int2*)(slab + s * SLABF + colLoc);
                unsigned x = (unsigned)u.x, y = (unsigned)u.y;
                a0 += __uint_as_float(x << 16); a1 += __uint_as_float(x & 0xFFFF0000u);
                a2 += __uint_as_float(y << 16); a3 += __uint_as_float(y & 0xFFFF0000u);
            }
        }

        if (alive) {
            float ri = rs_in[node];
            float v0 = fmaxf(a0 * ri + bb.x, 0.f);
            float v1 = fmaxf(a1 * ri + bb.y, 0.f);
            float v2 = fmaxf(a2 * ri + bb.z, 0.f);
            float v3 = fmaxf(a3 * ri + bb.w, 0.f);
            size_t o = (size_t)node * HID + col;
            if (residOut)
                __builtin_nontemporal_store((f32x4){v0, v1, v2, v3}, (f32x4*)(residOut + o));
            if (residIn) {
                f32x4 r = __builtin_nontemporal_load((const f32x4*)(residIn + o));
                v0 = fmaxf(v0 + r[0], 0.f);
                v1 = fmaxf(v1 + r[1], 0.f);
                v2 = fmaxf(v2 + r[2], 0.f);
                v3 = fmaxf(v3 + r[3], 0.f);
            }
            if (outXs) {
                float ro = rs_out[node];
                i32x2 h;
                h[0] = (int)(((unsigned)f2bf(v1 * ro) << 16) | f2bf(v0 * ro));
                h[1] = (int)(((unsigned)f2bf(v3 * ro) << 16) | f2bf(v2 * ro));
                __builtin_nontemporal_store(h, (i32x2*)(outXs + o));
            }
            if (outX)
                __builtin_nontemporal_store((f32x4){v0, v1, v2, v3}, (f32x4*)(outX + o));
        }
    }
}

// ---------------- final FC: out[n,41] = X[n,128] @ Wfc + bfc ----------------
__global__ __launch_bounds__(256) void fc_k(const float* __restrict__ X,
                                            const float* __restrict__ Wfc,
                                            const float* __restrict__ bfc,
                                            float* __restrict__ out, int n) {
    __shared__ float Ws[HID * OUTF];
    __shared__ float Xs[4][HID];
    int tid = threadIdx.x;
    for (int i = tid; i < HID * OUTF; i += 256) Ws[i] = Wfc[i];
    int rowBase = blockIdx.x * 4;
    for (int i = tid; i < 4 * HID; i += 256) {
        int r = i >> 7, c = i & 127;
        int gr = rowBase + r;
        Xs[r][c] = (gr < n) ? X[(size_t)gr * HID + c] : 0.f;
    }
    __syncthreads();
    int wv = tid >> 6, lane = tid & 63;
    int row = rowBase + wv;
    if (row < n && lane < OUTF) {
        float acc = bfc[lane];
#pragma unroll 8
        for (int k = 0; k < HID; ++k) acc += Xs[wv][k] * Ws[k * OUTF + lane];
        out[(size_t)row * OUTF + lane] = acc;
    }
}

extern "C" void kernel_launch(void* const* d_in, const int* in_sizes, int n_in,
                              void* d_out, int out_size, void* d_ws, size_t ws_size,
                              hipStream_t stream) {
    const float* feat = (const float*)d_in[0];
    const int* src = (const int*)d_in[1];
    const int* dst = (const int*)d_in[2];
    const float* W1 = (const float*)d_in[3];
    const float* b1 = (const float*)d_in[4];
    const float* W2 = (const float*)d_in[5];
    const float* b2 = (const float*)d_in[6];
    const float* W3 = (const float*)d_in[7];
    const float* b3 = (const float*)d_in[8];
    const float* Wfc = (const float*)d_in[9];
    const float* bfc = (const float*)d_in[10];
    float* out = (float*)d_out;

    char* w = (char*)d_ws;
    auto alloc = [&](size_t b) -> void* {
        void* p = (void*)w;
        w += (b + 255) & ~(size_t)255;
        return p;
    };
    int* cnt = (int*)alloc(2 * NN * sizeof(int));   // [cnt_out | cnt_in], zeroed in prep_all
    int* cnt_out = cnt;
    int* cnt_in  = cnt + NN;
    int* rowptr  = (int*)alloc((NN + 1) * sizeof(int));
    int* wcur    = (int*)alloc(NN * sizeof(int));
    int* csrsrc  = (int*)alloc(NE * sizeof(int));
    int* blockSum = (int*)alloc(NBLK * sizeof(int));
    float* rs_out = (float*)alloc(NN * sizeof(float));
    float* rs_in  = (float*)alloc(NN * sizeof(float));
    unsigned short* W1t = (unsigned short*)alloc(10 * 8192 * sizeof(unsigned short));
    unsigned short* W2t = (unsigned short*)alloc(16384 * sizeof(unsigned short));
    unsigned short* W3t = (unsigned short*)alloc(16384 * sizeof(unsigned short));
    unsigned short* Ha = (unsigned short*)alloc((size_t)NN * HID * sizeof(unsigned short));  // slab layout
    unsigned short* Hb = (unsigned short*)alloc((size_t)NN * HID * sizeof(unsigned short));  // slab layout
    unsigned short* Xb = (unsigned short*)alloc((size_t)NN * HID * sizeof(unsigned short));  // interleaved
    float* resid = (float*)alloc((size_t)NN * HID * sizeof(float));
    float* Xfc   = (float*)alloc((size_t)NN * HID * sizeof(float));

    prep_all_k<<<112, 256, 0, stream>>>(W1, W2, W3, W1t, W2t, W3t, cnt);
    deg_hist_k<<<(NE + 255) / 256, 256, 0, stream>>>(src, dst, cnt_out, cnt_in, NE);
    scan1_k<<<NBLK, 256, 0, stream>>>(cnt_in, rowptr, blockSum);
    scan23_k<<<NBLK, 256, 0, stream>>>(rowptr, blockSum, wcur, cnt_out, cnt_in, rs_out, rs_in);
    fill_csr_k<<<(NE + 255) / 256, 256, 0, stream>>>(src, dst, wcur, csrsrc, NE);

    const int gblk = (NN + 63) / 64;    // 782
    // L1 GEMM: Ha(slab) = bf16(rs_out ∘ (feat @ W1))
    gemm1_k<<<gblk, 256, 0, stream>>>(feat, W1t, rs_out, Ha, NN);
    // g1: Xb = bf16(relu(agg(Ha)*ri+b1) * ro)
    gath_slab_k<<<GBLKS, 256, 0, stream>>>(Ha, rowptr, csrsrc, rs_in, rs_out, b1,
                                           nullptr, nullptr, Xb, nullptr, NN);
    // L2 GEMM: Hb(slab) = bf16(Xb @ W2)
    gemm_hid_k<<<gblk, 256, 0, stream>>>(Xb, W2t, Hb, NN);
    // g2: resid = x2 fp32 (post-relu), Xb = bf16(x2 * ro)
    gath_slab_k<<<GBLKS, 256, 0, stream>>>(Hb, rowptr, csrsrc, rs_in, rs_out, b2,
                                           nullptr, resid, Xb, nullptr, NN);
    // L3 GEMM: Ha(slab) = bf16(Xb @ W3)
    gemm_hid_k<<<gblk, 256, 0, stream>>>(Xb, W3t, Ha, NN);
    // g3: Xfc = relu(relu(agg(Ha)*ri+b3) + resid)
    gath_slab_k<<<GBLKS, 256, 0, stream>>>(Ha, rowptr, csrsrc, rs_in, rs_out, b3,
                                           resid, nullptr, nullptr, Xfc, NN);
    // FC
    fc_k<<<(NN + 3) / 4, 256, 0, stream>>>(Xfc, Wfc, bfc, out, NN);
}

// Round 6
// 442.163 us; speedup vs baseline: 1.1838x; 1.1286x over previous
//
#include <hip/hip_runtime.h>
#include <hip/hip_bf16.h>

#define NN   50000
#define NE   600000
#define INF  602
#define HID  128
#define OUTF 41
#define NBLK 196   // ceil(NN/256)

#define HISTB 2344   // ceil(NE/256) blocks for edge-parallel work
#define GEMMB 782    // ceil(NN/64)

typedef __attribute__((ext_vector_type(8))) short bf16x8;
typedef __attribute__((ext_vector_type(4))) float f32x4;
typedef __attribute__((ext_vector_type(2))) float f32x2;

__device__ inline unsigned short f2bf(float x) {
    unsigned u = __float_as_uint(x);
    unsigned r = u + 0x7FFF + ((u >> 16) & 1);   // RNE
    return (unsigned short)(r >> 16);
}

__device__ inline f32x2 up2(unsigned u) {   // bf16 pair -> fp32 pair (lo, hi)
    return (f32x2){__uint_as_float(u << 16), __uint_as_float(u & 0xFFFF0000u)};
}

#define GLL16(gp, lp) \
    __builtin_amdgcn_global_load_lds((const __attribute__((address_space(1))) unsigned int*)(gp), \
                                     (__attribute__((address_space(3))) unsigned int*)(lp), 16, 0, 0)

// ---------------- weight prep body: fp32 [K][128] -> bf16 tiled [k>>3][col][k&7] ----------------
__device__ inline void prep_w_body(const float* __restrict__ W, int K,
                                   unsigned short* __restrict__ out, int total4, int i) {
    if (i >= total4) return;
    int col = i & 127;
    int k4 = (i >> 7) << 2;
    short4 h;
    h.x = (short)f2bf((k4 + 0 < K) ? W[(size_t)(k4 + 0) * HID + col] : 0.f);
    h.y = (short)f2bf((k4 + 1 < K) ? W[(size_t)(k4 + 1) * HID + col] : 0.f);
    h.z = (short)f2bf((k4 + 2 < K) ? W[(size_t)(k4 + 2) * HID + col] : 0.f);
    h.w = (short)f2bf((k4 + 3 < K) ? W[(size_t)(k4 + 3) * HID + col] : 0.f);
    *(short4*)&out[(size_t)(k4 >> 3) * 1024 + col * 8 + (k4 & 7)] = h;
}

// ---------------- K1: degree histogram + all weight prep (independent, one dispatch) ----------------
__global__ __launch_bounds__(256) void hist_prep_k(const int* __restrict__ src,
                                                   const int* __restrict__ dst,
                                                   int* __restrict__ cnt_out,
                                                   int* __restrict__ cnt_in,
                                                   const float* __restrict__ W1,
                                                   const float* __restrict__ W2,
                                                   const float* __restrict__ W3,
                                                   unsigned short* __restrict__ W1t,
                                                   unsigned short* __restrict__ W2t,
                                                   unsigned short* __restrict__ W3t) {
    int b = blockIdx.x;
    if (b < HISTB) {
        int e = b * 256 + threadIdx.x;
        if (e < NE) {
            atomicAdd(&cnt_out[src[e]], 1);
            atomicAdd(&cnt_in[dst[e]], 1);
        }
    } else {
        int b2 = b - HISTB;
        if (b2 < 80)       prep_w_body(W1, INF, W1t, 20480, b2 * 256 + threadIdx.x);
        else if (b2 < 96)  prep_w_body(W2, HID, W2t, 4096, (b2 - 80) * 256 + threadIdx.x);
        else               prep_w_body(W3, HID, W3t, 4096, (b2 - 96) * 256 + threadIdx.x);
    }
}

// ---------------- scan pass 1 ----------------
__global__ __launch_bounds__(256) void scan1_k(const int* __restrict__ cnt,
                                               int* __restrict__ rowptr,
                                               int* __restrict__ blockSum) {
    __shared__ int tmp[256];
    int tid = threadIdx.x;
    int i = blockIdx.x * 256 + tid;
    int v = (i < NN) ? cnt[i] : 0;
    tmp[tid] = v;
    __syncthreads();
#pragma unroll
    for (int off = 1; off < 256; off <<= 1) {
        int t = (tid >= off) ? tmp[tid - off] : 0;
        __syncthreads();
        tmp[tid] += t;
        __syncthreads();
    }
    if (i < NN) rowptr[i] = tmp[tid] - v;      // tile-exclusive
    if (tid == 255) blockSum[blockIdx.x] = tmp[255];
}

// ---------------- scan pass 2+3 fused ----------------
__global__ __launch_bounds__(256) void scan23_k(int* __restrict__ rowptr,
                                                const int* __restrict__ blockSum,
                                                int* __restrict__ wcur,
                                                const int* __restrict__ cnt_out,
                                                const int* __restrict__ cnt_in,
                                                float* __restrict__ rs_out,
                                                float* __restrict__ rs_in) {
    const int tid = threadIdx.x;
    const int bid = blockIdx.x;
    int vAll = (tid < NBLK) ? blockSum[tid] : 0;
    int vPre = (tid < bid) ? vAll : 0;
#pragma unroll
    for (int o = 32; o; o >>= 1) {
        vAll += __shfl_down(vAll, o);
        vPre += __shfl_down(vPre, o);
    }
    __shared__ int sA[4], sP[4];
    if ((tid & 63) == 0) { sA[tid >> 6] = vAll; sP[tid >> 6] = vPre; }
    __syncthreads();
    int offAll = sA[0] + sA[1] + sA[2] + sA[3];
    int offPre = sP[0] + sP[1] + sP[2] + sP[3];
    int i = bid * 256 + tid;
    if (i < NN) {
        int r = rowptr[i] + offPre;
        rowptr[i] = r;
        wcur[i] = r;
        int co = cnt_out[i]; if (co < 1) co = 1;
        int ci = cnt_in[i];  if (ci < 1) ci = 1;
        rs_out[i] = rsqrtf((float)co);
        rs_in[i]  = rsqrtf((float)ci);
    }
    if (bid == NBLK - 1 && tid == 0) rowptr[NN] = offAll;
}

// ---------------- K4: CSR fill + gemm1 fused (independent; fill blocks first) ----------------
// fill blocks (0..HISTB) turn over in ~12us at 3 blocks/CU; gemm blocks (49KB LDS) fill
// in behind them, so fill's ~25us hides entirely under gemm1's MFMA tail.
__global__ __launch_bounds__(256) void fill_gemm1_k(const int* __restrict__ src,
                                                    const int* __restrict__ dst,
                                                    int* __restrict__ wcur,
                                                    int* __restrict__ csrsrc,
                                                    const float* __restrict__ A,
                                                    const unsigned short* __restrict__ Wt,
                                                    const float* __restrict__ rs_out,
                                                    unsigned short* __restrict__ H, int n) {
    __shared__ __attribute__((aligned(16))) short As[64 * 136];   // 64 rows x 128 k, stride 136
    __shared__ __attribute__((aligned(16))) short Bs[16 * 1024];  // 16 kgroups x [col][8k]

    if (blockIdx.x < HISTB) {
        int e = blockIdx.x * 256 + threadIdx.x;
        if (e < NE) {
            int p = atomicAdd(&wcur[dst[e]], 1);
            csrsrc[p] = src[e];
        }
        return;
    }

    const int gb = blockIdx.x - HISTB;
    const int tid = threadIdx.x;
    const int wave = tid >> 6;
    const int lane = tid & 63;
    const int quad = lane >> 4;
    const int l16 = lane & 15;
    const int rowBase = gb * 64;
    const int tileBase = rowBase + wave * 16;

    float4 apf[8];
    auto loadA = [&](int ch) {   // coalesced: 32 consecutive lanes span one row's 128 floats
        int kb = ch * 128;
#pragma unroll
        for (int c = 0; c < 8; ++c) {
            int f = c * 256 + tid;
            int row = f >> 5;
            int kc = (f & 31) << 2;
            int grow = rowBase + row;
            int gk = kb + kc;
            float4 v = {0.f, 0.f, 0.f, 0.f};
            if (grow < n) {
                if (gk + 3 < INF) {
                    v = *(const float4*)(A + (size_t)grow * INF + gk);
                } else {
                    if (gk + 0 < INF) v.x = A[(size_t)grow * INF + gk + 0];
                    if (gk + 1 < INF) v.y = A[(size_t)grow * INF + gk + 1];
                    if (gk + 2 < INF) v.z = A[(size_t)grow * INF + gk + 2];
                }
            }
            apf[c] = v;
        }
    };
    auto storeA = [&]() {
#pragma unroll
        for (int c = 0; c < 8; ++c) {
            int f = c * 256 + tid;
            int row = f >> 5;
            int kc = (f & 31) << 2;
            short4 h;
            h.x = (short)f2bf(apf[c].x); h.y = (short)f2bf(apf[c].y);
            h.z = (short)f2bf(apf[c].z); h.w = (short)f2bf(apf[c].w);
            *(short4*)&As[row * 136 + kc] = h;
        }
    };
    auto issueB = [&](int ch) {  // 32KB = 32 x 1KB wave-DMA
#pragma unroll
        for (int c = 0; c < 8; ++c)
            GLL16(Wt + (size_t)ch * 16384 + c * 2048 + tid * 8, &Bs[c * 2048 + tid * 8]);
    };

    f32x4 acc[8];
#pragma unroll
    for (int j = 0; j < 8; ++j) acc[j] = (f32x4){0.f, 0.f, 0.f, 0.f};

    loadA(0);
    for (int ch = 0; ch < 5; ++ch) {
        __syncthreads();             // WAR: everyone done reading previous chunk's As/Bs
        issueB(ch);
        storeA();
        __syncthreads();             // arrival: DMA drained + As visible
        if (ch + 1 < 5) loadA(ch + 1);   // prefetch next A under this chunk's compute
#pragma unroll
        for (int s = 0; s < 4; ++s) {
            bf16x8 af = *(const bf16x8*)&As[(wave * 16 + l16) * 136 + s * 32 + quad * 8];
            const short* bg = &Bs[(s * 4 + quad) * 1024 + l16 * 8];
#pragma unroll
            for (int nt = 0; nt < 8; ++nt) {
                bf16x8 bf = *(const bf16x8*)(bg + nt * 128);
                acc[nt] = __builtin_amdgcn_mfma_f32_16x16x32_bf16(af, bf, acc[nt], 0, 0, 0);
            }
        }
    }

    // epilogue: C/D layout col = nt*16 + l16, row = tileBase + quad*4 + r
#pragma unroll
    for (int r = 0; r < 4; ++r) {
        int row = tileBase + quad * 4 + r;
        if (row < n) {
            float ro = rs_out[row];
#pragma unroll
            for (int nt = 0; nt < 8; ++nt)
                H[(size_t)row * HID + nt * 16 + l16] = f2bf(acc[nt][r] * ro);
        }
    }
}

// ============ gemm_hid: H[n,128] = bf16( Abf16[n,128] @ W[128,128] ), whole-W DMA to LDS ============
__global__ __launch_bounds__(256) void gemm_hid_k(const unsigned short* __restrict__ A,
                                                  const unsigned short* __restrict__ Wt,
                                                  unsigned short* __restrict__ H, int n) {
    __shared__ __attribute__((aligned(16))) short As[64 * 136];
    __shared__ __attribute__((aligned(16))) short Bs[16384];

    const int tid = threadIdx.x;
    const int wave = tid >> 6;
    const int lane = tid & 63;
    const int quad = lane >> 4;
    const int l16 = lane & 15;
    const int wm = wave >> 1;
    const int wn = wave & 1;
    const int rowBase = blockIdx.x * 64;

#pragma unroll
    for (int c = 0; c < 8; ++c)
        GLL16(Wt + c * 2048 + tid * 8, &Bs[c * 2048 + tid * 8]);

#pragma unroll
    for (int c = 0; c < 4; ++c) {
        int f = c * 256 + tid;
        int row = f >> 4;
        int k16 = (f & 15) << 3;
        int grow = rowBase + row;
        int4 v = {0, 0, 0, 0};
        if (grow < n) v = *(const int4*)(A + (size_t)grow * HID + k16);
        *(int4*)&As[row * 136 + k16] = v;
    }
    __syncthreads();

    f32x4 acc[2][4];
#pragma unroll
    for (int i = 0; i < 2; ++i)
#pragma unroll
        for (int j = 0; j < 4; ++j) acc[i][j] = (f32x4){0.f, 0.f, 0.f, 0.f};

#pragma unroll
    for (int kq = 0; kq < 4; ++kq) {
        bf16x8 af[2], bfr[4];
#pragma unroll
        for (int mt = 0; mt < 2; ++mt)
            af[mt] = *(const bf16x8*)&As[(wm * 32 + mt * 16 + l16) * 136 + kq * 32 + quad * 8];
#pragma unroll
        for (int nt = 0; nt < 4; ++nt)
            bfr[nt] = *(const bf16x8*)&Bs[(kq * 4 + quad) * 1024 + (wn * 64 + nt * 16 + l16) * 8];
#pragma unroll
        for (int mt = 0; mt < 2; ++mt)
#pragma unroll
            for (int nt = 0; nt < 4; ++nt)
                acc[mt][nt] = __builtin_amdgcn_mfma_f32_16x16x32_bf16(af[mt], bfr[nt], acc[mt][nt], 0, 0, 0);
    }

#pragma unroll
    for (int mt = 0; mt < 2; ++mt)
#pragma unroll
        for (int r = 0; r < 4; ++r) {
            int row = rowBase + wm * 32 + mt * 16 + quad * 4 + r;
            if (row < n) {
#pragma unroll
                for (int nt = 0; nt < 4; ++nt) {
                    int col = wn * 64 + nt * 16 + l16;
                    H[(size_t)row * HID + col] = f2bf(acc[mt][nt][r]);
                }
            }
        }
}

// ---------------- gather + finish (R2-proven structure, f32x2 packed adds) ----------------
// 4 nodes per wave, 16 lanes per node, one dwordx4 (16B = 8 bf16) per edge-row per group.
// float2 accumulators let the compiler emit v_pk_add_f32 (same per-feature add order).
__global__ __launch_bounds__(256) void gather_k(const unsigned short* __restrict__ H,
                                                const int* __restrict__ rowptr,
                                                const int* __restrict__ csrsrc,
                                                const float* __restrict__ rs_in,
                                                const float* __restrict__ rs_out,
                                                const float* __restrict__ bias,
                                                const float* __restrict__ resid,     // nullable (added)
                                                float* __restrict__ outX,            // nullable
                                                unsigned short* __restrict__ outXs,  // nullable (bf16)
                                                int n) {
    const int lane = threadIdx.x & 63;
    const int g = lane >> 4;          // group (node slot) 0..3
    const int l = lane & 15;          // lane within group
    const int gbase = g << 4;
    const int wid = blockIdx.x * 4 + (threadIdx.x >> 6);
    const int node = wid * 4 + g;
    const bool alive = node < n;

    int beg = 0, end = 0;
    if (alive) { beg = rowptr[node]; end = rowptr[node + 1]; }

    f32x2 a01 = {0.f, 0.f}, a23 = {0.f, 0.f}, a45 = {0.f, 0.f}, a67 = {0.f, 0.f};

    for (int base = beg; base < end; base += 16) {
        int m = end - base; if (m > 16) m = 16;
        int idx = (l < m) ? csrsrc[base + l] : 0;   // one coalesced 64B load per group-chunk
        int j = 0;
        for (; j + 3 < m; j += 4) {
            int s0 = __shfl(idx, gbase | j);
            int s1 = __shfl(idx, gbase | (j + 1));
            int s2 = __shfl(idx, gbase | (j + 2));
            int s3 = __shfl(idx, gbase | (j + 3));
            int4 u0 = *(const int4*)(H + (size_t)s0 * HID + l * 8);
            int4 u1 = *(const int4*)(H + (size_t)s1 * HID + l * 8);
            int4 u2 = *(const int4*)(H + (size_t)s2 * HID + l * 8);
            int4 u3 = *(const int4*)(H + (size_t)s3 * HID + l * 8);
#pragma unroll
            for (int q = 0; q < 4; ++q) {
                int4 u = (q == 0) ? u0 : (q == 1) ? u1 : (q == 2) ? u2 : u3;
                a01 += up2((unsigned)u.x);
                a23 += up2((unsigned)u.y);
                a45 += up2((unsigned)u.z);
                a67 += up2((unsigned)u.w);
            }
        }
        for (; j < m; ++j) {
            int s = __shfl(idx, gbase | j);
            int4 u = *(const int4*)(H + (size_t)s * HID + l * 8);
            a01 += up2((unsigned)u.x);
            a23 += up2((unsigned)u.y);
            a45 += up2((unsigned)u.z);
            a67 += up2((unsigned)u.w);
        }
    }

    if (!alive) return;

    float ri = rs_in[node];
    float4 b0 = *(const float4*)(bias + l * 8);
    float4 b1 = *(const float4*)(bias + l * 8 + 4);
    float v[8];
    v[0] = fmaxf(a01[0] * ri + b0.x, 0.f); v[1] = fmaxf(a01[1] * ri + b0.y, 0.f);
    v[2] = fmaxf(a23[0] * ri + b0.z, 0.f); v[3] = fmaxf(a23[1] * ri + b0.w, 0.f);
    v[4] = fmaxf(a45[0] * ri + b1.x, 0.f); v[5] = fmaxf(a45[1] * ri + b1.y, 0.f);
    v[6] = fmaxf(a67[0] * ri + b1.z, 0.f); v[7] = fmaxf(a67[1] * ri + b1.w, 0.f);

    size_t o = (size_t)node * HID + l * 8;
    if (resid) {
        float4 r0 = *(const float4*)(resid + o);
        float4 r1 = *(const float4*)(resid + o + 4);
        v[0] = fmaxf(v[0] + r0.x, 0.f); v[1] = fmaxf(v[1] + r0.y, 0.f);
        v[2] = fmaxf(v[2] + r0.z, 0.f); v[3] = fmaxf(v[3] + r0.w, 0.f);
        v[4] = fmaxf(v[4] + r1.x, 0.f); v[5] = fmaxf(v[5] + r1.y, 0.f);
        v[6] = fmaxf(v[6] + r1.z, 0.f); v[7] = fmaxf(v[7] + r1.w, 0.f);
    }
    if (outX) {
        *(float4*)(outX + o) = make_float4(v[0], v[1], v[2], v[3]);
        *(float4*)(outX + o + 4) = make_float4(v[4], v[5], v[6], v[7]);
    }
    if (outXs) {
        float ro = rs_out[node];
        int4 h;
        h.x = (int)(((unsigned)f2bf(v[1] * ro) << 16) | f2bf(v[0] * ro));
        h.y = (int)(((unsigned)f2bf(v[3] * ro) << 16) | f2bf(v[2] * ro));
        h.z = (int)(((unsigned)f2bf(v[5] * ro) << 16) | f2bf(v[4] * ro));
        h.w = (int)(((unsigned)f2bf(v[7] * ro) << 16) | f2bf(v[6] * ro));
        *(int4*)(outXs + o) = h;
    }
}

// ---------------- final FC: out[n,41] = X[n,128] @ Wfc + bfc ----------------
__global__ __launch_bounds__(256) void fc_k(const float* __restrict__ X,
                                            const float* __restrict__ Wfc,
                                            const float* __restrict__ bfc,
                                            float* __restrict__ out, int n) {
    __shared__ float Ws[HID * OUTF];
    __shared__ float Xs[4][HID];
    int tid = threadIdx.x;
    for (int i = tid; i < HID * OUTF; i += 256) Ws[i] = Wfc[i];
    int rowBase = blockIdx.x * 4;
    for (int i = tid; i < 4 * HID; i += 256) {
        int r = i >> 7, c = i & 127;
        int gr = rowBase + r;
        Xs[r][c] = (gr < n) ? X[(size_t)gr * HID + c] : 0.f;
    }
    __syncthreads();
    int wv = tid >> 6, lane = tid & 63;
    int row = rowBase + wv;
    if (row < n && lane < OUTF) {
        float acc = bfc[lane];
#pragma unroll 8
        for (int k = 0; k < HID; ++k) acc += Xs[wv][k] * Ws[k * OUTF + lane];
        out[(size_t)row * OUTF + lane] = acc;
    }
}

extern "C" void kernel_launch(void* const* d_in, const int* in_sizes, int n_in,
                              void* d_out, int out_size, void* d_ws, size_t ws_size,
                              hipStream_t stream) {
    const float* feat = (const float*)d_in[0];
    const int* src = (const int*)d_in[1];
    const int* dst = (const int*)d_in[2];
    const float* W1 = (const float*)d_in[3];
    const float* b1 = (const float*)d_in[4];
    const float* W2 = (const float*)d_in[5];
    const float* b2 = (const float*)d_in[6];
    const float* W3 = (const float*)d_in[7];
    const float* b3 = (const float*)d_in[8];
    const float* Wfc = (const float*)d_in[9];
    const float* bfc = (const float*)d_in[10];
    float* out = (float*)d_out;

    char* w = (char*)d_ws;
    auto alloc = [&](size_t b) -> void* {
        void* p = (void*)w;
        w += (b + 255) & ~(size_t)255;
        return p;
    };
    int* cnt = (int*)alloc(2 * NN * sizeof(int));   // [cnt_out | cnt_in]
    int* cnt_out = cnt;
    int* cnt_in  = cnt + NN;
    int* rowptr  = (int*)alloc((NN + 1) * sizeof(int));
    int* wcur    = (int*)alloc(NN * sizeof(int));
    int* csrsrc  = (int*)alloc(NE * sizeof(int));
    int* blockSum = (int*)alloc(NBLK * sizeof(int));
    float* rs_out = (float*)alloc(NN * sizeof(float));
    float* rs_in  = (float*)alloc(NN * sizeof(float));
    unsigned short* W1t = (unsigned short*)alloc(10 * 8192 * sizeof(unsigned short));
    unsigned short* W2t = (unsigned short*)alloc(16384 * sizeof(unsigned short));
    unsigned short* W3t = (unsigned short*)alloc(16384 * sizeof(unsigned short));
    unsigned short* Ha = (unsigned short*)alloc((size_t)NN * HID * sizeof(unsigned short));
    unsigned short* Hb = (unsigned short*)alloc((size_t)NN * HID * sizeof(unsigned short));
    unsigned short* Xb = (unsigned short*)alloc((size_t)NN * HID * sizeof(unsigned short));
    float* resid = (float*)alloc((size_t)NN * HID * sizeof(float));
    float* Xfc   = (float*)alloc((size_t)NN * HID * sizeof(float));

    hipMemsetAsync(cnt, 0, 2 * NN * sizeof(int), stream);

    // K1: histogram + all weight prep (independent block ranges)
    hist_prep_k<<<HISTB + 112, 256, 0, stream>>>(src, dst, cnt_out, cnt_in,
                                                 W1, W2, W3, W1t, W2t, W3t);
    // K2/K3: scan
    scan1_k<<<NBLK, 256, 0, stream>>>(cnt_in, rowptr, blockSum);
    scan23_k<<<NBLK, 256, 0, stream>>>(rowptr, blockSum, wcur, cnt_out, cnt_in, rs_out, rs_in);
    // K4: CSR fill (blocks 0..HISTB) + L1 GEMM (blocks HISTB..): Ha = bf16(rs_out ∘ (feat @ W1))
    fill_gemm1_k<<<HISTB + GEMMB, 256, 0, stream>>>(src, dst, wcur, csrsrc,
                                                    feat, W1t, rs_out, Ha, NN);

    const int ablk = (NN + 15) / 16;    // 3125: 16 nodes per block (4 per wave)
    // g1: Xb = bf16(relu(agg(Ha)*ri+b1) * ro)
    gather_k<<<ablk, 256, 0, stream>>>(Ha, rowptr, csrsrc, rs_in, rs_out, b1,
                                       nullptr, nullptr, Xb, NN);
    // L2 GEMM: Hb = bf16(Xb @ W2)
    gemm_hid_k<<<GEMMB, 256, 0, stream>>>(Xb, W2t, Hb, NN);
    // g2: resid = x2 fp32 (post-relu), Xb = bf16(x2 * ro)
    gather_k<<<ablk, 256, 0, stream>>>(Hb, rowptr, csrsrc, rs_in, rs_out, b2,
                                       nullptr, resid, Xb, NN);
    // L3 GEMM: Ha = bf16(Xb @ W3)
    gemm_hid_k<<<GEMMB, 256, 0, stream>>>(Xb, W3t, Ha, NN);
    // g3: Xfc = relu(relu(agg(Ha)*ri+b3) + resid)
    gather_k<<<ablk, 256, 0, stream>>>(Ha, rowptr, csrsrc, rs_in, rs_out, b3,
                                       resid, Xfc, nullptr, NN);
    // FC
    fc_k<<<(NN + 3) / 4, 256, 0, stream>>>(Xfc, Wfc, bfc, out, NN);
}